// Round 1
// baseline (562.282 us; speedup 1.0000x reference)
//
#include <hip/hip_runtime.h>

#define NNODES 50000
#define NEDGES 800000
#define IN_FEAT 512
#define HIDDEN 64
#define N_CLASS 16
#define RPW 16   // rows per wave in gemm1

// ---------------- GEMM1: h0 = x @ W1  [n,512]@[512,64] ----------------
// wave = 64 lanes = 64 output columns; RPW rows per wave.
// W1 staged 32 k-slices at a time in VGPRs; x rows read via wave-uniform
// (readfirstlane) pointers -> scalar loads, x streamed exactly once.
__global__ __launch_bounds__(256) void k_gemm1(const float* __restrict__ x,
                                               const float* __restrict__ W1,
                                               float* __restrict__ h0, int n) {
    int wid  = blockIdx.x * 4 + (threadIdx.x >> 6);
    int lane = threadIdx.x & 63;
    int row0 = wid * RPW;
    if (row0 >= n) return;
    float acc[RPW];
#pragma unroll
    for (int r = 0; r < RPW; ++r) acc[r] = 0.f;

    for (int c = 0; c < IN_FEAT; c += 32) {
        float w[32];
#pragma unroll
        for (int kk = 0; kk < 32; ++kk) w[kk] = W1[(c + kk) * HIDDEN + lane];
#pragma unroll
        for (int r = 0; r < RPW; ++r) {
            const float* xr =
                x + (size_t)__builtin_amdgcn_readfirstlane(row0 + r) * IN_FEAT + c;
#pragma unroll
            for (int kk = 0; kk < 32; ++kk) acc[r] = fmaf(xr[kk], w[kk], acc[r]);
        }
    }
#pragma unroll
    for (int r = 0; r < RPW; ++r)
        h0[(size_t)(row0 + r) * HIDDEN + lane] = acc[r];
}

// ---------------- CSR build ----------------
__global__ __launch_bounds__(256) void k_degree(const int* __restrict__ dst,
                                                int* __restrict__ deg, int E) {
    int i = blockIdx.x * 256 + threadIdx.x;
    if (i < E) atomicAdd(&deg[dst[i]], 1);
}

// per-256-block exclusive scan; block totals to bsum
__global__ __launch_bounds__(256) void k_scan1(const int* __restrict__ deg,
                                               int* __restrict__ rp,
                                               int* __restrict__ bsum, int n) {
    __shared__ int lds[4];
    int i = blockIdx.x * 256 + threadIdx.x;
    int v = (i < n) ? deg[i] : 0;
    int lane = threadIdx.x & 63, wv = threadIdx.x >> 6;
    int s = v;
#pragma unroll
    for (int d = 1; d < 64; d <<= 1) {
        int t = __shfl_up(s, d, 64);
        if (lane >= d) s += t;
    }
    if (lane == 63) lds[wv] = s;
    __syncthreads();
    int base = 0;
    for (int w2 = 0; w2 < wv; ++w2) base += lds[w2];
    if (i < n) rp[i] = base + s - v;                 // exclusive within block
    if (threadIdx.x == 255) bsum[blockIdx.x] = base + s;  // block total
}

// single-block exclusive scan of block sums (nb <= 256)
__global__ __launch_bounds__(256) void k_scan2(const int* __restrict__ bsum,
                                               int* __restrict__ boff, int nb) {
    __shared__ int lds[4];
    int i = threadIdx.x;
    int v = (i < nb) ? bsum[i] : 0;
    int lane = i & 63, wv = i >> 6;
    int s = v;
#pragma unroll
    for (int d = 1; d < 64; d <<= 1) {
        int t = __shfl_up(s, d, 64);
        if (lane >= d) s += t;
    }
    if (lane == 63) lds[wv] = s;
    __syncthreads();
    int base = 0;
    for (int w2 = 0; w2 < wv; ++w2) base += lds[w2];
    if (i < nb) boff[i] = base + s - v;
}

__global__ __launch_bounds__(256) void k_scan3(int* __restrict__ rp,
                                               int* __restrict__ cursor,
                                               const int* __restrict__ boff,
                                               int n, int E) {
    int i = blockIdx.x * 256 + threadIdx.x;
    if (i < n) {
        int v = rp[i] + boff[i >> 8];
        rp[i] = v;
        cursor[i] = v;
    }
    if (i == 0) rp[n] = E;
}

__global__ __launch_bounds__(256) void k_scatter(const int* __restrict__ src,
                                                 const int* __restrict__ dst,
                                                 const float* __restrict__ ew,
                                                 int* __restrict__ cursor,
                                                 int* __restrict__ psrc,
                                                 float* __restrict__ pw, int E) {
    int i = blockIdx.x * 256 + threadIdx.x;
    if (i < E) {
        int d = dst[i];
        int pos = atomicAdd(&cursor[d], 1);
        psrc[pos] = src[i];
        pw[pos]  = ew[i];
    }
}

// ---------------- SPMM1 + bias + relu: h1 = relu(A@h0 + b1) ----------------
// wave per node, lane = feature (64)
__global__ __launch_bounds__(256) void k_spmm1(const int* __restrict__ rp,
                                               const int* __restrict__ psrc,
                                               const float* __restrict__ pw,
                                               const float* __restrict__ h0,
                                               const float* __restrict__ b1,
                                               float* __restrict__ h1, int n) {
    int wid  = blockIdx.x * 4 + (threadIdx.x >> 6);
    int lane = threadIdx.x & 63;
    if (wid >= n) return;
    int node = __builtin_amdgcn_readfirstlane(wid);
    int beg = rp[node], end = rp[node + 1];
    float acc = 0.f;
    for (int e = beg; e < end; ++e) {
        int s   = psrc[e];
        float w = pw[e];
        acc = fmaf(w, h0[(size_t)s * HIDDEN + lane], acc);
    }
    float v = acc + b1[lane];
    h1[(size_t)node * HIDDEN + lane] = v > 0.f ? v : 0.f;
}

// ---------------- GEMM2: h2 = h1 @ W2  [n,64]@[64,16] ----------------
// wave = 4 rows x 16 cols
__global__ __launch_bounds__(256) void k_gemm2(const float* __restrict__ h1,
                                               const float* __restrict__ W2,
                                               float* __restrict__ h2, int n) {
    int wid  = blockIdx.x * 4 + (threadIdx.x >> 6);
    int lane = threadIdx.x & 63;
    int row  = wid * 4 + (lane >> 4);
    int f    = lane & 15;
    if (row >= n) return;
    float acc = 0.f;
#pragma unroll
    for (int k = 0; k < HIDDEN; ++k)
        acc = fmaf(h1[(size_t)row * HIDDEN + k], W2[k * N_CLASS + f], acc);
    h2[(size_t)row * N_CLASS + f] = acc;
}

// ---------------- SPMM2 + bias + softmax ----------------
// wave = 4 nodes x 16 classes; softmax via 16-lane shfl reductions
__global__ __launch_bounds__(256) void k_spmm2(const int* __restrict__ rp,
                                               const int* __restrict__ psrc,
                                               const float* __restrict__ pw,
                                               const float* __restrict__ h2,
                                               const float* __restrict__ b2,
                                               float* __restrict__ out, int n) {
    int wid  = blockIdx.x * 4 + (threadIdx.x >> 6);
    int lane = threadIdx.x & 63;
    int node = wid * 4 + (lane >> 4);
    int f    = lane & 15;
    if (node >= n) return;
    int beg = rp[node], end = rp[node + 1];
    float acc = 0.f;
    for (int e = beg; e < end; ++e)
        acc = fmaf(pw[e], h2[(size_t)psrc[e] * N_CLASS + f], acc);
    float logit = acc + b2[f];
    float m = logit;
#pragma unroll
    for (int d = 1; d < 16; d <<= 1) m = fmaxf(m, __shfl_xor(m, d, 16));
    float ex = __expf(logit - m);
    float s = ex;
#pragma unroll
    for (int d = 1; d < 16; d <<= 1) s += __shfl_xor(s, d, 16);
    out[(size_t)node * N_CLASS + f] = ex / s;
}

extern "C" void kernel_launch(void* const* d_in, const int* in_sizes, int n_in,
                              void* d_out, int out_size, void* d_ws, size_t ws_size,
                              hipStream_t stream) {
    const float* x   = (const float*)d_in[0];
    const int*   src = (const int*)d_in[1];
    const int*   dst = (const int*)d_in[2];
    const float* ew  = (const float*)d_in[3];
    const float* W1  = (const float*)d_in[4];
    const float* b1  = (const float*)d_in[5];
    const float* W2  = (const float*)d_in[6];
    const float* b2  = (const float*)d_in[7];
    float* out = (float*)d_out;

    int n = in_sizes[0] / IN_FEAT;  // 50000
    int E = in_sizes[1];            // 800000

    // workspace layout
    float* h0   = (float*)d_ws;              // n*64
    float* h1   = h0 + (size_t)n * HIDDEN;   // n*64
    float* h2   = h1 + (size_t)n * HIDDEN;   // n*16
    float* pw   = h2 + (size_t)n * N_CLASS;  // E
    int*   psrc = (int*)(pw + E);            // E
    int*   deg  = psrc + E;                  // n
    int*   rp   = deg + n;                   // n+1
    int*   cursor = rp + n + 1;              // n
    int*   bsum = cursor + n;                // <=256
    int*   boff = bsum + 256;                // <=256

    int nb = (n + 255) / 256;  // 196 scan blocks
    int eb = (E + 255) / 256;  // edge blocks

    hipMemsetAsync(deg, 0, (size_t)n * sizeof(int), stream);
    k_degree<<<eb, 256, 0, stream>>>(dst, deg, E);
    k_scan1<<<nb, 256, 0, stream>>>(deg, rp, bsum, n);
    k_scan2<<<1, 256, 0, stream>>>(bsum, boff, nb);
    k_scan3<<<nb, 256, 0, stream>>>(rp, cursor, boff, n, E);
    k_scatter<<<eb, 256, 0, stream>>>(src, dst, ew, cursor, psrc, pw, E);

    int g1_waves  = (n + RPW - 1) / RPW;           // 3125
    int g1_blocks = (g1_waves + 3) / 4;            // 782
    k_gemm1<<<g1_blocks, 256, 0, stream>>>(x, W1, h0, n);
    k_spmm1<<<(n + 3) / 4, 256, 0, stream>>>(rp, psrc, pw, h0, b1, h1, n);
    k_gemm2<<<(n + 15) / 16, 256, 0, stream>>>(h1, W2, h2, n);
    k_spmm2<<<(n + 15) / 16, 256, 0, stream>>>(rp, psrc, pw, h2, b2, out, n);
}

// Round 2
// 363.872 us; speedup vs baseline: 1.5453x; 1.5453x over previous
//
#include <hip/hip_runtime.h>

#define NNODES 50000
#define NEDGES 800000
#define IN_FEAT 512
#define HIDDEN 64
#define N_CLASS 16

typedef __attribute__((ext_vector_type(8))) short bf16x8;
typedef __attribute__((ext_vector_type(8))) unsigned short ushort8;
typedef __attribute__((ext_vector_type(4))) float f32x4;

__device__ inline unsigned short f2bf(float f) {
    union { float f; unsigned int u; } x; x.f = f;
    unsigned int u = x.u + 0x7FFFu + ((x.u >> 16) & 1u);  // RNE
    return (unsigned short)(u >> 16);
}

// ---- W1 -> B-fragment order (bf16), done once per call, tiny ----
// layout: for kc in [0,16), ct in [0,4), lane in [0,64):
//   bfrag[((kc*4+ct)*64 + lane)*8 + j] = bf16(W1[kc*32 + (lane>>4)*8 + j][ct*16 + (lane&15)])
__global__ __launch_bounds__(256) void k_prep_w1(const float* __restrict__ W1,
                                                 unsigned short* __restrict__ bfrag) {
    int t = blockIdx.x * 256 + threadIdx.x;   // [0, 4096)
    int l = t & 63;
    int grp = t >> 6;          // kc*4 + ct
    int ct = grp & 3, kc = grp >> 2;
    int k0 = kc * 32 + (l >> 4) * 8;
    int col = ct * 16 + (l & 15);
    ushort8 v;
#pragma unroll
    for (int j = 0; j < 8; ++j) v[j] = f2bf(W1[(k0 + j) * HIDDEN + col]);
    ((ushort8*)bfrag)[t] = v;
}

// ---- GEMM1: h0 = x @ W1 via bf16 MFMA, wave = 16 rows x 64 cols ----
__global__ __launch_bounds__(256) void k_gemm1_mfma(const float* __restrict__ x,
                                                    const unsigned short* __restrict__ bfrag,
                                                    float* __restrict__ h0, int n) {
    int wid  = blockIdx.x * 4 + (threadIdx.x >> 6);
    int lane = threadIdx.x & 63;
    int r0 = wid * 16;
    if (r0 >= n) return;
    const float* xp = x + (size_t)(r0 + (lane & 15)) * IN_FEAT + (lane >> 4) * 8;
    const bf16x8* B = (const bf16x8*)bfrag;

    f32x4 acc0 = {0,0,0,0}, acc1 = {0,0,0,0}, acc2 = {0,0,0,0}, acc3 = {0,0,0,0};

#pragma unroll
    for (int kc = 0; kc < 16; ++kc) {
        f32x4 a0 = *(const f32x4*)(xp + kc * 32);
        f32x4 a1 = *(const f32x4*)(xp + kc * 32 + 4);
        bf16x8 a;
#pragma unroll
        for (int j = 0; j < 4; ++j) a[j] = (short)f2bf(a0[j]);
#pragma unroll
        for (int j = 0; j < 4; ++j) a[4 + j] = (short)f2bf(a1[j]);
        bf16x8 b0 = B[(kc * 4 + 0) * 64 + lane];
        bf16x8 b1 = B[(kc * 4 + 1) * 64 + lane];
        bf16x8 b2 = B[(kc * 4 + 2) * 64 + lane];
        bf16x8 b3 = B[(kc * 4 + 3) * 64 + lane];
        acc0 = __builtin_amdgcn_mfma_f32_16x16x32_bf16(a, b0, acc0, 0, 0, 0);
        acc1 = __builtin_amdgcn_mfma_f32_16x16x32_bf16(a, b1, acc1, 0, 0, 0);
        acc2 = __builtin_amdgcn_mfma_f32_16x16x32_bf16(a, b2, acc2, 0, 0, 0);
        acc3 = __builtin_amdgcn_mfma_f32_16x16x32_bf16(a, b3, acc3, 0, 0, 0);
    }

    // D layout: col = ct*16 + (lane&15), row = r0 + (lane>>4)*4 + j
    int c = lane & 15;
    int rb = r0 + ((lane >> 4) << 2);
#pragma unroll
    for (int j = 0; j < 4; ++j) {
        float* o = h0 + (size_t)(rb + j) * HIDDEN;
        o[ 0 + c] = acc0[j];
        o[16 + c] = acc1[j];
        o[32 + c] = acc2[j];
        o[48 + c] = acc3[j];
    }
}

// ---------------- CSR build ----------------
__global__ __launch_bounds__(256) void k_degree(const int* __restrict__ dst,
                                                int* __restrict__ deg, int E) {
    int i = blockIdx.x * 256 + threadIdx.x;
    if (i < E) atomicAdd(&deg[dst[i]], 1);
}

__global__ __launch_bounds__(256) void k_scan1(const int* __restrict__ deg,
                                               int* __restrict__ rp,
                                               int* __restrict__ bsum, int n) {
    __shared__ int lds[4];
    int i = blockIdx.x * 256 + threadIdx.x;
    int v = (i < n) ? deg[i] : 0;
    int lane = threadIdx.x & 63, wv = threadIdx.x >> 6;
    int s = v;
#pragma unroll
    for (int d = 1; d < 64; d <<= 1) {
        int t = __shfl_up(s, d, 64);
        if (lane >= d) s += t;
    }
    if (lane == 63) lds[wv] = s;
    __syncthreads();
    int base = 0;
    for (int w2 = 0; w2 < wv; ++w2) base += lds[w2];
    if (i < n) rp[i] = base + s - v;
    if (threadIdx.x == 255) bsum[blockIdx.x] = base + s;
}

__global__ __launch_bounds__(256) void k_scan2(const int* __restrict__ bsum,
                                               int* __restrict__ boff, int nb) {
    __shared__ int lds[4];
    int i = threadIdx.x;
    int v = (i < nb) ? bsum[i] : 0;
    int lane = i & 63, wv = i >> 6;
    int s = v;
#pragma unroll
    for (int d = 1; d < 64; d <<= 1) {
        int t = __shfl_up(s, d, 64);
        if (lane >= d) s += t;
    }
    if (lane == 63) lds[wv] = s;
    __syncthreads();
    int base = 0;
    for (int w2 = 0; w2 < wv; ++w2) base += lds[w2];
    if (i < nb) boff[i] = base + s - v;
}

__global__ __launch_bounds__(256) void k_scan3(int* __restrict__ rp,
                                               int* __restrict__ cursor,
                                               const int* __restrict__ boff,
                                               int n, int E) {
    int i = blockIdx.x * 256 + threadIdx.x;
    if (i < n) {
        int v = rp[i] + boff[i >> 8];
        rp[i] = v;
        cursor[i] = v;
    }
    if (i == 0) rp[n] = E;
}

__global__ __launch_bounds__(256) void k_scatter(const int* __restrict__ src,
                                                 const int* __restrict__ dst,
                                                 const float* __restrict__ ew,
                                                 int* __restrict__ cursor,
                                                 int* __restrict__ psrc,
                                                 float* __restrict__ pw, int E) {
    int i = blockIdx.x * 256 + threadIdx.x;
    if (i < E) {
        int d = dst[i];
        int pos = atomicAdd(&cursor[d], 1);
        psrc[pos] = src[i];
        pw[pos]  = ew[i];
    }
}

// ---------------- SPMM1 + bias + relu ----------------
__global__ __launch_bounds__(256) void k_spmm1(const int* __restrict__ rp,
                                               const int* __restrict__ psrc,
                                               const float* __restrict__ pw,
                                               const float* __restrict__ h0,
                                               const float* __restrict__ b1,
                                               float* __restrict__ h1, int n) {
    int wid  = blockIdx.x * 4 + (threadIdx.x >> 6);
    int lane = threadIdx.x & 63;
    if (wid >= n) return;
    int node = __builtin_amdgcn_readfirstlane(wid);
    int beg = rp[node], end = rp[node + 1];
    float acc = 0.f;
    for (int e = beg; e < end; ++e) {
        int s   = psrc[e];
        float w = pw[e];
        acc = fmaf(w, h0[(size_t)s * HIDDEN + lane], acc);
    }
    float v = acc + b1[lane];
    h1[(size_t)node * HIDDEN + lane] = v > 0.f ? v : 0.f;
}

// ---------------- GEMM2: h2 = h1 @ W2 ----------------
__global__ __launch_bounds__(256) void k_gemm2(const float* __restrict__ h1,
                                               const float* __restrict__ W2,
                                               float* __restrict__ h2, int n) {
    int wid  = blockIdx.x * 4 + (threadIdx.x >> 6);
    int lane = threadIdx.x & 63;
    int row  = wid * 4 + (lane >> 4);
    int f    = lane & 15;
    if (row >= n) return;
    float acc = 0.f;
#pragma unroll
    for (int k = 0; k < HIDDEN; ++k)
        acc = fmaf(h1[(size_t)row * HIDDEN + k], W2[k * N_CLASS + f], acc);
    h2[(size_t)row * N_CLASS + f] = acc;
}

// ---------------- SPMM2 + bias + softmax ----------------
__global__ __launch_bounds__(256) void k_spmm2(const int* __restrict__ rp,
                                               const int* __restrict__ psrc,
                                               const float* __restrict__ pw,
                                               const float* __restrict__ h2,
                                               const float* __restrict__ b2,
                                               float* __restrict__ out, int n) {
    int wid  = blockIdx.x * 4 + (threadIdx.x >> 6);
    int lane = threadIdx.x & 63;
    int node = wid * 4 + (lane >> 4);
    int f    = lane & 15;
    if (node >= n) return;
    int beg = rp[node], end = rp[node + 1];
    float acc = 0.f;
    for (int e = beg; e < end; ++e)
        acc = fmaf(pw[e], h2[(size_t)psrc[e] * N_CLASS + f], acc);
    float logit = acc + b2[f];
    float m = logit;
#pragma unroll
    for (int d = 1; d < 16; d <<= 1) m = fmaxf(m, __shfl_xor(m, d, 16));
    float ex = __expf(logit - m);
    float s = ex;
#pragma unroll
    for (int d = 1; d < 16; d <<= 1) s += __shfl_xor(s, d, 16);
    out[(size_t)node * N_CLASS + f] = ex / s;
}

extern "C" void kernel_launch(void* const* d_in, const int* in_sizes, int n_in,
                              void* d_out, int out_size, void* d_ws, size_t ws_size,
                              hipStream_t stream) {
    const float* x   = (const float*)d_in[0];
    const int*   src = (const int*)d_in[1];
    const int*   dst = (const int*)d_in[2];
    const float* ew  = (const float*)d_in[3];
    const float* W1  = (const float*)d_in[4];
    const float* b1  = (const float*)d_in[5];
    const float* W2  = (const float*)d_in[6];
    const float* b2  = (const float*)d_in[7];
    float* out = (float*)d_out;

    int n = in_sizes[0] / IN_FEAT;  // 50000
    int E = in_sizes[1];            // 800000

    // workspace layout
    float* h0   = (float*)d_ws;              // n*64
    float* h1   = h0 + (size_t)n * HIDDEN;   // n*64
    float* h2   = h1 + (size_t)n * HIDDEN;   // n*16
    float* pw   = h2 + (size_t)n * N_CLASS;  // E
    int*   psrc = (int*)(pw + E);            // E
    int*   deg  = psrc + E;                  // n
    int*   rp   = deg + n;                   // n+1
    int*   cursor = rp + n + 1;              // n
    int*   bsum = cursor + n;                // <=256
    int*   boff = bsum + 256;                // <=256
    unsigned short* bfrag = (unsigned short*)(boff + 256);  // 512*64 bf16 = 64KB

    int nb = (n + 255) / 256;
    int eb = (E + 255) / 256;

    hipMemsetAsync(deg, 0, (size_t)n * sizeof(int), stream);
    k_prep_w1<<<16, 256, 0, stream>>>(W1, bfrag);
    k_degree<<<eb, 256, 0, stream>>>(dst, deg, E);
    k_scan1<<<nb, 256, 0, stream>>>(deg, rp, bsum, n);
    k_scan2<<<1, 256, 0, stream>>>(bsum, boff, nb);
    k_scan3<<<nb, 256, 0, stream>>>(rp, cursor, boff, n, E);
    k_scatter<<<eb, 256, 0, stream>>>(src, dst, ew, cursor, psrc, pw, E);

    int g1_waves  = (n + 15) / 16;                 // 3125
    int g1_blocks = (g1_waves + 3) / 4;
    k_gemm1_mfma<<<g1_blocks, 256, 0, stream>>>(x, bfrag, h0, n);
    k_spmm1<<<(n + 3) / 4, 256, 0, stream>>>(rp, psrc, pw, h0, b1, h1, n);
    k_gemm2<<<(n + 15) / 16, 256, 0, stream>>>(h1, W2, h2, n);
    k_spmm2<<<(n + 15) / 16, 256, 0, stream>>>(rp, psrc, pw, h2, b2, out, n);
}

// Round 3
// 363.378 us; speedup vs baseline: 1.5474x; 1.0014x over previous
//
#include <hip/hip_runtime.h>

#define NNODES 50000
#define NEDGES 800000
#define IN_FEAT 512
#define HIDDEN 64
#define N_CLASS 16

typedef __attribute__((ext_vector_type(8))) short bf16x8;
typedef __attribute__((ext_vector_type(8))) unsigned short ushort8;
typedef __attribute__((ext_vector_type(4))) float f32x4;

struct EdgeRec { int s; float w; };   // packed 8B record

__device__ inline unsigned short f2bf(float f) {
    union { float f; unsigned int u; } x; x.f = f;
    unsigned int u = x.u + 0x7FFFu + ((x.u >> 16) & 1u);  // RNE
    return (unsigned short)(u >> 16);
}

// ---- W1 -> B-fragment order (bf16), done once per call, tiny ----
__global__ __launch_bounds__(256) void k_prep_w1(const float* __restrict__ W1,
                                                 unsigned short* __restrict__ bfrag) {
    int t = blockIdx.x * 256 + threadIdx.x;   // [0, 4096)
    int l = t & 63;
    int grp = t >> 6;          // kc*4 + ct
    int ct = grp & 3, kc = grp >> 2;
    int k0 = kc * 32 + (l >> 4) * 8;
    int col = ct * 16 + (l & 15);
    ushort8 v;
#pragma unroll
    for (int j = 0; j < 8; ++j) v[j] = f2bf(W1[(k0 + j) * HIDDEN + col]);
    ((ushort8*)bfrag)[t] = v;
}

// ---- GEMM1: h0 = x @ W1 via bf16 MFMA, wave = 16 rows x 64 cols ----
__global__ __launch_bounds__(256) void k_gemm1_mfma(const float* __restrict__ x,
                                                    const unsigned short* __restrict__ bfrag,
                                                    float* __restrict__ h0, int n) {
    int wid  = blockIdx.x * 4 + (threadIdx.x >> 6);
    int lane = threadIdx.x & 63;
    int r0 = wid * 16;
    if (r0 >= n) return;
    const float* xp = x + (size_t)(r0 + (lane & 15)) * IN_FEAT + (lane >> 4) * 8;
    const bf16x8* B = (const bf16x8*)bfrag;

    f32x4 acc0 = {0,0,0,0}, acc1 = {0,0,0,0}, acc2 = {0,0,0,0}, acc3 = {0,0,0,0};

#pragma unroll
    for (int kc = 0; kc < 16; ++kc) {
        f32x4 a0 = *(const f32x4*)(xp + kc * 32);
        f32x4 a1 = *(const f32x4*)(xp + kc * 32 + 4);
        bf16x8 a;
#pragma unroll
        for (int j = 0; j < 4; ++j) a[j] = (short)f2bf(a0[j]);
#pragma unroll
        for (int j = 0; j < 4; ++j) a[4 + j] = (short)f2bf(a1[j]);
        bf16x8 b0 = B[(kc * 4 + 0) * 64 + lane];
        bf16x8 b1 = B[(kc * 4 + 1) * 64 + lane];
        bf16x8 b2 = B[(kc * 4 + 2) * 64 + lane];
        bf16x8 b3 = B[(kc * 4 + 3) * 64 + lane];
        acc0 = __builtin_amdgcn_mfma_f32_16x16x32_bf16(a, b0, acc0, 0, 0, 0);
        acc1 = __builtin_amdgcn_mfma_f32_16x16x32_bf16(a, b1, acc1, 0, 0, 0);
        acc2 = __builtin_amdgcn_mfma_f32_16x16x32_bf16(a, b2, acc2, 0, 0, 0);
        acc3 = __builtin_amdgcn_mfma_f32_16x16x32_bf16(a, b3, acc3, 0, 0, 0);
    }

    int c = lane & 15;
    int rb = r0 + ((lane >> 4) << 2);
#pragma unroll
    for (int j = 0; j < 4; ++j) {
        float* o = h0 + (size_t)(rb + j) * HIDDEN;
        o[ 0 + c] = acc0[j];
        o[16 + c] = acc1[j];
        o[32 + c] = acc2[j];
        o[48 + c] = acc3[j];
    }
}

// ---------------- CSR build ----------------
__global__ __launch_bounds__(256) void k_degree(const int* __restrict__ dst,
                                                int* __restrict__ deg, int E) {
    int i = blockIdx.x * 256 + threadIdx.x;
    if (i < E) atomicAdd(&deg[dst[i]], 1);
}

__global__ __launch_bounds__(256) void k_scan1(const int* __restrict__ deg,
                                               int* __restrict__ rp,
                                               int* __restrict__ bsum, int n) {
    __shared__ int lds[4];
    int i = blockIdx.x * 256 + threadIdx.x;
    int v = (i < n) ? deg[i] : 0;
    int lane = threadIdx.x & 63, wv = threadIdx.x >> 6;
    int s = v;
#pragma unroll
    for (int d = 1; d < 64; d <<= 1) {
        int t = __shfl_up(s, d, 64);
        if (lane >= d) s += t;
    }
    if (lane == 63) lds[wv] = s;
    __syncthreads();
    int base = 0;
    for (int w2 = 0; w2 < wv; ++w2) base += lds[w2];
    if (i < n) rp[i] = base + s - v;
    if (threadIdx.x == 255) bsum[blockIdx.x] = base + s;
}

__global__ __launch_bounds__(256) void k_scan2(const int* __restrict__ bsum,
                                               int* __restrict__ boff, int nb) {
    __shared__ int lds[4];
    int i = threadIdx.x;
    int v = (i < nb) ? bsum[i] : 0;
    int lane = i & 63, wv = i >> 6;
    int s = v;
#pragma unroll
    for (int d = 1; d < 64; d <<= 1) {
        int t = __shfl_up(s, d, 64);
        if (lane >= d) s += t;
    }
    if (lane == 63) lds[wv] = s;
    __syncthreads();
    int base = 0;
    for (int w2 = 0; w2 < wv; ++w2) base += lds[w2];
    if (i < nb) boff[i] = base + s - v;
}

__global__ __launch_bounds__(256) void k_scan3(int* __restrict__ rp,
                                               int* __restrict__ cursor,
                                               const int* __restrict__ boff,
                                               int n, int E) {
    int i = blockIdx.x * 256 + threadIdx.x;
    if (i < n) {
        int v = rp[i] + boff[i >> 8];
        rp[i] = v;
        cursor[i] = v;
    }
    if (i == 0) rp[n] = E;
}

// one packed 8B store per edge (was 2x 4B to separate arrays)
__global__ __launch_bounds__(256) void k_scatter(const int* __restrict__ src,
                                                 const int* __restrict__ dst,
                                                 const float* __restrict__ ew,
                                                 int* __restrict__ cursor,
                                                 EdgeRec* __restrict__ recs, int E) {
    int i = blockIdx.x * 256 + threadIdx.x;
    if (i < E) {
        int d = dst[i];
        int pos = atomicAdd(&cursor[d], 1);
        EdgeRec r; r.s = src[i]; r.w = ew[i];
        recs[pos] = r;
    }
}

// ---------------- SPMM1 + bias + relu ----------------
__global__ __launch_bounds__(256) void k_spmm1(const int* __restrict__ rp,
                                               const EdgeRec* __restrict__ recs,
                                               const float* __restrict__ h0,
                                               const float* __restrict__ b1,
                                               float* __restrict__ h1, int n) {
    int wid  = blockIdx.x * 4 + (threadIdx.x >> 6);
    int lane = threadIdx.x & 63;
    if (wid >= n) return;
    int node = __builtin_amdgcn_readfirstlane(wid);
    int beg = rp[node], end = rp[node + 1];
    float acc = 0.f;
    for (int e = beg; e < end; ++e) {
        EdgeRec r = recs[e];
        acc = fmaf(r.w, h0[(size_t)r.s * HIDDEN + lane], acc);
    }
    float v = acc + b1[lane];
    h1[(size_t)node * HIDDEN + lane] = v > 0.f ? v : 0.f;
}

// ---------------- GEMM2: h2 = h1 @ W2 ----------------
__global__ __launch_bounds__(256) void k_gemm2(const float* __restrict__ h1,
                                               const float* __restrict__ W2,
                                               float* __restrict__ h2, int n) {
    int wid  = blockIdx.x * 4 + (threadIdx.x >> 6);
    int lane = threadIdx.x & 63;
    int row  = wid * 4 + (lane >> 4);
    int f    = lane & 15;
    if (row >= n) return;
    float acc = 0.f;
#pragma unroll
    for (int k = 0; k < HIDDEN; ++k)
        acc = fmaf(h1[(size_t)row * HIDDEN + k], W2[k * N_CLASS + f], acc);
    h2[(size_t)row * N_CLASS + f] = acc;
}

// ---------------- SPMM2 + bias + softmax ----------------
__global__ __launch_bounds__(256) void k_spmm2(const int* __restrict__ rp,
                                               const EdgeRec* __restrict__ recs,
                                               const float* __restrict__ h2,
                                               const float* __restrict__ b2,
                                               float* __restrict__ out, int n) {
    int wid  = blockIdx.x * 4 + (threadIdx.x >> 6);
    int lane = threadIdx.x & 63;
    int node = wid * 4 + (lane >> 4);
    int f    = lane & 15;
    if (node >= n) return;
    int beg = rp[node], end = rp[node + 1];
    float acc = 0.f;
    for (int e = beg; e < end; ++e) {
        EdgeRec r = recs[e];
        acc = fmaf(r.w, h2[(size_t)r.s * N_CLASS + f], acc);
    }
    float logit = acc + b2[f];
    float m = logit;
#pragma unroll
    for (int d = 1; d < 16; d <<= 1) m = fmaxf(m, __shfl_xor(m, d, 16));
    float ex = __expf(logit - m);
    float s = ex;
#pragma unroll
    for (int d = 1; d < 16; d <<= 1) s += __shfl_xor(s, d, 16);
    out[(size_t)node * N_CLASS + f] = ex / s;
}

extern "C" void kernel_launch(void* const* d_in, const int* in_sizes, int n_in,
                              void* d_out, int out_size, void* d_ws, size_t ws_size,
                              hipStream_t stream) {
    const float* x   = (const float*)d_in[0];
    const int*   src = (const int*)d_in[1];
    const int*   dst = (const int*)d_in[2];
    const float* ew  = (const float*)d_in[3];
    const float* W1  = (const float*)d_in[4];
    const float* b1  = (const float*)d_in[5];
    const float* W2  = (const float*)d_in[6];
    const float* b2  = (const float*)d_in[7];
    float* out = (float*)d_out;

    int n = in_sizes[0] / IN_FEAT;  // 50000
    int E = in_sizes[1];            // 800000

    // workspace layout
    float*   h0   = (float*)d_ws;              // n*64
    float*   h1   = h0 + (size_t)n * HIDDEN;   // n*64
    float*   h2   = h1 + (size_t)n * HIDDEN;   // n*16
    EdgeRec* recs = (EdgeRec*)(h2 + (size_t)n * N_CLASS);  // E * 8B
    int*     deg  = (int*)(recs + E);          // n
    int*     rp   = deg + n;                   // n+1
    int*     cursor = rp + n + 1;              // n
    int*     bsum = cursor + n;                // <=256
    int*     boff = bsum + 256;                // <=256
    unsigned short* bfrag = (unsigned short*)(boff + 256);  // 512*64 bf16 = 64KB

    int nb = (n + 255) / 256;
    int eb = (E + 255) / 256;

    hipMemsetAsync(deg, 0, (size_t)n * sizeof(int), stream);
    k_prep_w1<<<16, 256, 0, stream>>>(W1, bfrag);
    k_degree<<<eb, 256, 0, stream>>>(dst, deg, E);
    k_scan1<<<nb, 256, 0, stream>>>(deg, rp, bsum, n);
    k_scan2<<<1, 256, 0, stream>>>(bsum, boff, nb);
    k_scan3<<<nb, 256, 0, stream>>>(rp, cursor, boff, n, E);
    k_scatter<<<eb, 256, 0, stream>>>(src, dst, ew, cursor, recs, E);

    int g1_waves  = (n + 15) / 16;                 // 3125
    int g1_blocks = (g1_waves + 3) / 4;
    k_gemm1_mfma<<<g1_blocks, 256, 0, stream>>>(x, bfrag, h0, n);
    k_spmm1<<<(n + 3) / 4, 256, 0, stream>>>(rp, recs, h0, b1, h1, n);
    k_gemm2<<<(n + 15) / 16, 256, 0, stream>>>(h1, W2, h2, n);
    k_spmm2<<<(n + 15) / 16, 256, 0, stream>>>(rp, recs, h2, b2, out, n);
}